// Round 9
// baseline (317.634 us; speedup 1.0000x reference)
//
#include <hip/hip_runtime.h>
#include <hip/hip_bf16.h>

// GraphSAGE 2-layer. Persistent fused kernel: double-buffered LDS tile pipeline,
// gather(t+1) register-staged and issued UNDER GEMM(t); sched_barrier(0) pins order.
// N_RAW=200000, N1=100000 (3125 tiles of 32), N2=20000 (625 tiles), D=256, OUT=256.

typedef __attribute__((ext_vector_type(8))) short bf16x8;
typedef __attribute__((ext_vector_type(4))) float f32x4;

static __device__ __forceinline__ short f2bf(float f) {
  __hip_bfloat16 h = __float2bfloat16(f);
  return *reinterpret_cast<short*>(&h);
}
static __device__ __forceinline__ float bf2f(short s) {
  union { unsigned u; float f; } x;
  x.u = ((unsigned)(unsigned short)s) << 16;
  return x.f;
}

// ---------------- one-shot f32 -> bf16: raw (25000 blocks) + W1 (64) + W2 (64) ----------------
__global__ __launch_bounds__(256) void convert_all(
    const float* __restrict__ raw, const float* __restrict__ W1,
    const float* __restrict__ W2, short* __restrict__ rawb,
    short* __restrict__ W1b, short* __restrict__ W2b) {
  const int b = blockIdx.x;
  const float* src;
  short* dst;
  size_t base;
  if (b < 25000) { src = raw; dst = rawb; base = (size_t)b * 2048; }
  else if (b < 25064) { src = W1; dst = W1b; base = (size_t)(b - 25000) * 2048; }
  else { src = W2; dst = W2b; base = (size_t)(b - 25064) * 2048; }
  const size_t i = base + (size_t)threadIdx.x * 8;
  const f32x4* s4 = reinterpret_cast<const f32x4*>(src + i);
  f32x4 u = __builtin_nontemporal_load(s4);
  f32x4 v = __builtin_nontemporal_load(s4 + 1);
  bf16x8 o;
  o[0] = f2bf(u.x); o[1] = f2bf(u.y); o[2] = f2bf(u.z); o[3] = f2bf(u.w);
  o[4] = f2bf(v.x); o[5] = f2bf(v.y); o[6] = f2bf(v.z); o[7] = f2bf(v.w);
  *reinterpret_cast<bf16x8*>(dst + i) = o;
}

// ---------------- persistent pipelined fused layer ----------------
// 512 threads (8 waves). Gather role: thread (c=tid&31 chunk, rs=tid>>5 slot)
// owns rows rs*2+rr of each tile. GEMM role: wave w -> cols w*32..+31.
// Per tile t: GEMM(t) from As[buf]; staged gather of tile t+1 -> As[buf^1];
// one __syncthreads per tile.
template <bool OUT_BF16>
__global__ __launch_bounds__(512, 4) void sage_pipe(
    const short* __restrict__ E,        // [Ne][256] bf16 embeddings
    const int* __restrict__ self_idx,   // [Nv]
    const int* __restrict__ neigh,      // [Nv][10]
    const short* __restrict__ Wb,       // [256][512] bf16 (W row-major)
    void* __restrict__ out,             // [Nv][256] (bf16 or f32)
    int ntiles) {
  __shared__ short As[2][32][520];  // 66,560 B -> 2 blocks/CU

  const int tid = threadIdx.x;
  const int nblk = gridDim.x;
  const int start = (int)(((long long)blockIdx.x * ntiles) / nblk);
  const int end = (int)(((long long)(blockIdx.x + 1) * ntiles) / nblk);
  if (start >= end) return;

  const int c = tid & 31;    // 16-B chunk within 256-col row
  const int rs = tid >> 5;   // row slot 0..15 -> rows rs*2, rs*2+1

  const int wave = tid >> 6, lane = tid & 63;
  const int wn = wave * 32;
  const int lr = lane & 15;
  const int lkb = (lane >> 4) * 8;
  const short* Bp = Wb + (size_t)(wn + lr) * 512 + lkb;  // + nf*8192 + ks*32

  auto load_idx = [&](int t, int rr, int* nbx, int& six)
      __attribute__((always_inline)) {
    const int gr = t * 32 + rs * 2 + rr;
#pragma unroll
    for (int k = 0; k < 10; ++k) nbx[k] = neigh[gr * 10 + k];
    six = self_idx[gr];
  };
  auto issue_feat = [&](const int* nbx, int six, bf16x8* v)
      __attribute__((always_inline)) {
#pragma unroll
    for (int k = 0; k < 10; ++k)
      v[k] = *reinterpret_cast<const bf16x8*>(E + (size_t)(unsigned)nbx[k] * 256 + c * 8);
    v[10] = *reinterpret_cast<const bf16x8*>(E + (size_t)(unsigned)six * 256 + c * 8);
  };
  auto reduce_write = [&](int rr, int buf, const bf16x8* v)
      __attribute__((always_inline)) {
    const int r = rs * 2 + rr;
    bf16x8 mv;
#pragma unroll
    for (int j = 0; j < 8; ++j) {
      float sA = bf2f(v[0][j]) + bf2f(v[2][j]) + bf2f(v[4][j]) + bf2f(v[6][j]) + bf2f(v[8][j]);
      float sB = bf2f(v[1][j]) + bf2f(v[3][j]) + bf2f(v[5][j]) + bf2f(v[7][j]) + bf2f(v[9][j]);
      mv[j] = f2bf((sA + sB) * 0.1f);
    }
    *reinterpret_cast<bf16x8*>(&As[buf][r][c * 8]) = v[10];
    *reinterpret_cast<bf16x8*>(&As[buf][r][256 + c * 8]) = mv;
  };

  // staged pipeline state
  bf16x8 vs[11];       // features in flight for the next half-tile
  int nbxN[10], sixN;  // indices for the half-tile after that

  // ---- prologue: gather tile `start` unpipelined into buf 0 ----
#pragma unroll
  for (int rr = 0; rr < 2; ++rr) {
    int nbx[10], six;
    load_idx(start, rr, nbx, six);
    bf16x8 v[11];
    issue_feat(nbx, six, v);
    reduce_write(rr, 0, v);
  }
  if (start + 1 < end) {
    int nbx0[10], six0;
    load_idx(start + 1, 0, nbx0, six0);
    issue_feat(nbx0, six0, vs);          // (start+1, r0) in flight
    load_idx(start + 1, 1, nbxN, sixN);  // idx for (start+1, r1)
  }
  __syncthreads();

  for (int t = start; t < end; ++t) {
    const int buf = (t - start) & 1;
    const bool hn = (t + 1 < end);
    const bool hn2 = (t + 2 < end);
    f32x4 acc[2][2] = {};

    // ---- step A: GEMM ks 0..7 (loads for (t+1,r0) fly underneath) ----
#pragma unroll
    for (int ks = 0; ks < 8; ++ks) {
      bf16x8 a0 = *reinterpret_cast<const bf16x8*>(&As[buf][lr][ks * 32 + lkb]);
      bf16x8 a1 = *reinterpret_cast<const bf16x8*>(&As[buf][16 + lr][ks * 32 + lkb]);
      bf16x8 b0 = *reinterpret_cast<const bf16x8*>(Bp + ks * 32);
      bf16x8 b1 = *reinterpret_cast<const bf16x8*>(Bp + ks * 32 + 8192);
      __builtin_amdgcn_s_setprio(1);
      acc[0][0] = __builtin_amdgcn_mfma_f32_16x16x32_bf16(a0, b0, acc[0][0], 0, 0, 0);
      acc[1][0] = __builtin_amdgcn_mfma_f32_16x16x32_bf16(a1, b0, acc[1][0], 0, 0, 0);
      acc[0][1] = __builtin_amdgcn_mfma_f32_16x16x32_bf16(a0, b1, acc[0][1], 0, 0, 0);
      acc[1][1] = __builtin_amdgcn_mfma_f32_16x16x32_bf16(a1, b1, acc[1][1], 0, 0, 0);
      __builtin_amdgcn_s_setprio(0);
    }
    __builtin_amdgcn_sched_barrier(0);
    if (hn) {
      reduce_write(0, buf ^ 1, vs);      // consume (t+1,r0)
      issue_feat(nbxN, sixN, vs);        // issue (t+1,r1)
    }
    __builtin_amdgcn_sched_barrier(0);
    if (hn2) load_idx(t + 2, 0, nbxN, sixN);
    __builtin_amdgcn_sched_barrier(0);

    // ---- step B: GEMM ks 8..15 ((t+1,r1) loads fly underneath) ----
#pragma unroll
    for (int ks = 8; ks < 16; ++ks) {
      bf16x8 a0 = *reinterpret_cast<const bf16x8*>(&As[buf][lr][ks * 32 + lkb]);
      bf16x8 a1 = *reinterpret_cast<const bf16x8*>(&As[buf][16 + lr][ks * 32 + lkb]);
      bf16x8 b0 = *reinterpret_cast<const bf16x8*>(Bp + ks * 32);
      bf16x8 b1 = *reinterpret_cast<const bf16x8*>(Bp + ks * 32 + 8192);
      __builtin_amdgcn_s_setprio(1);
      acc[0][0] = __builtin_amdgcn_mfma_f32_16x16x32_bf16(a0, b0, acc[0][0], 0, 0, 0);
      acc[1][0] = __builtin_amdgcn_mfma_f32_16x16x32_bf16(a1, b0, acc[1][0], 0, 0, 0);
      acc[0][1] = __builtin_amdgcn_mfma_f32_16x16x32_bf16(a0, b1, acc[0][1], 0, 0, 0);
      acc[1][1] = __builtin_amdgcn_mfma_f32_16x16x32_bf16(a1, b1, acc[1][1], 0, 0, 0);
      __builtin_amdgcn_s_setprio(0);
    }
    __builtin_amdgcn_sched_barrier(0);
    if (hn) reduce_write(1, buf ^ 1, vs);  // consume (t+1,r1)
    if (hn2) {
      issue_feat(nbxN, sixN, vs);          // issue (t+2,r0)
      load_idx(t + 2, 1, nbxN, sixN);      // idx for (t+2,r1)
    }
    __builtin_amdgcn_sched_barrier(0);

    // ---- epilogue: relu + store tile t ----
#pragma unroll
    for (int mi = 0; mi < 2; ++mi)
#pragma unroll
      for (int ni = 0; ni < 2; ++ni)
#pragma unroll
        for (int r = 0; r < 4; ++r) {
          const int gm = t * 32 + mi * 16 + (lane >> 4) * 4 + r;
          const int gn = wn + ni * 16 + lr;
          float v = acc[mi][ni][r];
          v = v > 0.f ? v : 0.f;
          if (OUT_BF16)
            reinterpret_cast<short*>(out)[(size_t)gm * 256 + gn] = f2bf(v);
          else
            reinterpret_cast<float*>(out)[(size_t)gm * 256 + gn] = v;
        }
    __syncthreads();
  }
}

extern "C" void kernel_launch(void* const* d_in, const int* in_sizes, int n_in,
                              void* d_out, int out_size, void* d_ws, size_t ws_size,
                              hipStream_t stream) {
  const float* raw = (const float*)d_in[0];
  const float* W1 = (const float*)d_in[1];
  const float* W2 = (const float*)d_in[2];
  const int* nodes1 = (const int*)d_in[3];
  const int* neigh1 = (const int*)d_in[4];
  const int* self2 = (const int*)d_in[5];
  const int* neigh2 = (const int*)d_in[6];
  float* out = (float*)d_out;

  const int N_RAW = 200000, N1 = 100000;

  short* rawb = (short*)d_ws;                         // 200000*256 bf16 = 102.4 MB
  short* h1 = rawb + (size_t)N_RAW * 256;             // 100000*256 bf16 = 51.2 MB
  short* W1b = h1 + (size_t)N1 * 256;                 // 131072 bf16
  short* W2b = W1b + 131072;                          // 131072 bf16

  convert_all<<<25128, 256, 0, stream>>>(raw, W1, W2, rawb, W1b, W2b);
  sage_pipe<true><<<512, 512, 0, stream>>>(rawb, nodes1, neigh1, W1b, h1, 3125);
  sage_pipe<false><<<512, 512, 0, stream>>>(h1, self2, neigh2, W2b, out, 625);
}

// Round 10
// 204.556 us; speedup vs baseline: 1.5528x; 1.5528x over previous
//
#include <hip/hip_runtime.h>
#include <hip/hip_bf16.h>

// GraphSAGE 2-layer, fused per-block {gather+mean -> LDS} then {MFMA GEMM}.
// Round 10: 64-row tiles (halve W re-streaming, 2x MFMA per B-load), 512 threads,
// 2 blocks/CU (LDS 66.5KB), VGPR cap 128 -> 1-step B-prefetch fits.
// N_RAW=200000, N1=100000 (1563 tiles), N2=20000 (313 tiles), D=256, OUT=256.

typedef __attribute__((ext_vector_type(8))) short bf16x8;
typedef __attribute__((ext_vector_type(4))) float f32x4;

static __device__ __forceinline__ short f2bf(float f) {
  __hip_bfloat16 h = __float2bfloat16(f);
  return *reinterpret_cast<short*>(&h);
}
static __device__ __forceinline__ float bf2f(short s) {
  union { unsigned u; float f; } x;
  x.u = ((unsigned)(unsigned short)s) << 16;
  return x.f;
}

// ---------------- one-shot f32 -> bf16: raw (25000 blocks) + W1 (64) + W2 (64) ----------------
// NT loads: don't pollute L2/LLC with the 205 MB f32 stream; rawb stays LLC-resident.
__global__ __launch_bounds__(256) void convert_all(
    const float* __restrict__ raw, const float* __restrict__ W1,
    const float* __restrict__ W2, short* __restrict__ rawb,
    short* __restrict__ W1b, short* __restrict__ W2b) {
  const int b = blockIdx.x;
  const float* src;
  short* dst;
  size_t base;
  if (b < 25000) { src = raw; dst = rawb; base = (size_t)b * 2048; }
  else if (b < 25064) { src = W1; dst = W1b; base = (size_t)(b - 25000) * 2048; }
  else { src = W2; dst = W2b; base = (size_t)(b - 25064) * 2048; }
  const size_t i = base + (size_t)threadIdx.x * 8;
  const f32x4* s4 = reinterpret_cast<const f32x4*>(src + i);
  f32x4 u = __builtin_nontemporal_load(s4);
  f32x4 v = __builtin_nontemporal_load(s4 + 1);
  bf16x8 o;
  o[0] = f2bf(u.x); o[1] = f2bf(u.y); o[2] = f2bf(u.z); o[3] = f2bf(u.w);
  o[4] = f2bf(v.x); o[5] = f2bf(v.y); o[6] = f2bf(v.z); o[7] = f2bf(v.w);
  *reinterpret_cast<bf16x8*>(dst + i) = o;
}

// ---------------- fused layer: gather+mean -> LDS -> relu(comb @ W^T) ----------------
// Block: 64 rows x 256 cols, 512 threads (8 waves), one 66.5 KB LDS tile.
// Gather: thread (c=tid&31 chunk, rs=tid>>5 slot 0..15) does rows rs*4..rs*4+3.
// GEMM: wave w -> cols w*32..+31; 4 m-frags x 2 n-frags; B-prefetch 1 k-step ahead.
template <bool OUT_BF16>
__global__ __launch_bounds__(512, 4) void sage_fused(
    const short* __restrict__ E,        // [Ne][256] bf16 embeddings
    const int* __restrict__ self_idx,   // [Nv]
    const int* __restrict__ neigh,      // [Nv][10]
    const short* __restrict__ Wb,       // [256][512] bf16 (W row-major)
    void* __restrict__ out,             // [Nv][256] (bf16 or f32)
    int Nvalid) {
  __shared__ short As[64][520];  // row stride 1040 B

  const int tid = threadIdx.x;
  const int m0 = blockIdx.x * 64;
  const int c = tid & 31;    // 16-B chunk (8 bf16) within 256-col row
  const int rs = tid >> 5;   // row slot 0..15 -> rows rs*4 .. rs*4+3

  // ---- gather + mean: 4 serial row-batches per thread ----
#pragma unroll
  for (int rr = 0; rr < 4; ++rr) {
    const int r = rs * 4 + rr;
    int gr = m0 + r;
    gr = gr < Nvalid ? gr : Nvalid - 1;  // clamp (tail tile): dummy but valid
    const int si = self_idx[gr];
    int nbx[10];
#pragma unroll
    for (int k = 0; k < 10; ++k) nbx[k] = neigh[gr * 10 + k];
    bf16x8 sv = *reinterpret_cast<const bf16x8*>(E + (size_t)(unsigned)si * 256 + c * 8);
    bf16x8 v[10];
#pragma unroll
    for (int k = 0; k < 10; ++k)
      v[k] = *reinterpret_cast<const bf16x8*>(E + (size_t)(unsigned)nbx[k] * 256 + c * 8);
    bf16x8 mv;
#pragma unroll
    for (int j = 0; j < 8; ++j) {
      float sA = bf2f(v[0][j]) + bf2f(v[2][j]) + bf2f(v[4][j]) + bf2f(v[6][j]) + bf2f(v[8][j]);
      float sB = bf2f(v[1][j]) + bf2f(v[3][j]) + bf2f(v[5][j]) + bf2f(v[7][j]) + bf2f(v[9][j]);
      mv[j] = f2bf((sA + sB) * 0.1f);
    }
    *reinterpret_cast<bf16x8*>(&As[r][c * 8]) = sv;
    *reinterpret_cast<bf16x8*>(&As[r][256 + c * 8]) = mv;
  }
  __syncthreads();

  // ---- GEMM phase: 64 rows x 256 cols = 8 waves x (64x32), K=512 ----
  const int wave = tid >> 6, lane = tid & 63;
  const int wn = wave * 32;
  const int lr = lane & 15;           // m (A) / n (B) within 16x16 frag
  const int lkb = (lane >> 4) * 8;    // k base within 32
  const short* Bp = Wb + (size_t)(wn + lr) * 512 + lkb;  // + nf*8192 + ks*32

  f32x4 acc[4][2] = {};

  // B prefetch for ks=0
  bf16x8 b0 = *reinterpret_cast<const bf16x8*>(Bp);
  bf16x8 b1 = *reinterpret_cast<const bf16x8*>(Bp + 8192);

#pragma unroll
  for (int ks = 0; ks < 16; ++ks) {
    bf16x8 nb0, nb1;
    if (ks < 15) {
      nb0 = *reinterpret_cast<const bf16x8*>(Bp + (ks + 1) * 32);
      nb1 = *reinterpret_cast<const bf16x8*>(Bp + (ks + 1) * 32 + 8192);
    }
    bf16x8 a0 = *reinterpret_cast<const bf16x8*>(&As[lr][ks * 32 + lkb]);
    bf16x8 a1 = *reinterpret_cast<const bf16x8*>(&As[16 + lr][ks * 32 + lkb]);
    bf16x8 a2 = *reinterpret_cast<const bf16x8*>(&As[32 + lr][ks * 32 + lkb]);
    bf16x8 a3 = *reinterpret_cast<const bf16x8*>(&As[48 + lr][ks * 32 + lkb]);
    __builtin_amdgcn_s_setprio(1);
    acc[0][0] = __builtin_amdgcn_mfma_f32_16x16x32_bf16(a0, b0, acc[0][0], 0, 0, 0);
    acc[1][0] = __builtin_amdgcn_mfma_f32_16x16x32_bf16(a1, b0, acc[1][0], 0, 0, 0);
    acc[2][0] = __builtin_amdgcn_mfma_f32_16x16x32_bf16(a2, b0, acc[2][0], 0, 0, 0);
    acc[3][0] = __builtin_amdgcn_mfma_f32_16x16x32_bf16(a3, b0, acc[3][0], 0, 0, 0);
    acc[0][1] = __builtin_amdgcn_mfma_f32_16x16x32_bf16(a0, b1, acc[0][1], 0, 0, 0);
    acc[1][1] = __builtin_amdgcn_mfma_f32_16x16x32_bf16(a1, b1, acc[1][1], 0, 0, 0);
    acc[2][1] = __builtin_amdgcn_mfma_f32_16x16x32_bf16(a2, b1, acc[2][1], 0, 0, 0);
    acc[3][1] = __builtin_amdgcn_mfma_f32_16x16x32_bf16(a3, b1, acc[3][1], 0, 0, 0);
    __builtin_amdgcn_s_setprio(0);
    b0 = nb0; b1 = nb1;
  }

  // ---- epilogue: relu + store (C/D: col=lane&15, row=(lane>>4)*4+reg) ----
#pragma unroll
  for (int mi = 0; mi < 4; ++mi)
#pragma unroll
    for (int ni = 0; ni < 2; ++ni)
#pragma unroll
      for (int r = 0; r < 4; ++r) {
        const int gm = m0 + mi * 16 + (lane >> 4) * 4 + r;
        const int gn = wn + ni * 16 + lr;
        float v = acc[mi][ni][r];
        v = v > 0.f ? v : 0.f;
        if (gm < Nvalid) {
          if (OUT_BF16)
            reinterpret_cast<short*>(out)[(size_t)gm * 256 + gn] = f2bf(v);
          else
            reinterpret_cast<float*>(out)[(size_t)gm * 256 + gn] = v;
        }
      }
}

extern "C" void kernel_launch(void* const* d_in, const int* in_sizes, int n_in,
                              void* d_out, int out_size, void* d_ws, size_t ws_size,
                              hipStream_t stream) {
  const float* raw = (const float*)d_in[0];
  const float* W1 = (const float*)d_in[1];
  const float* W2 = (const float*)d_in[2];
  const int* nodes1 = (const int*)d_in[3];
  const int* neigh1 = (const int*)d_in[4];
  const int* self2 = (const int*)d_in[5];
  const int* neigh2 = (const int*)d_in[6];
  float* out = (float*)d_out;

  const int N_RAW = 200000, N1 = 100000, N2 = 20000;

  short* rawb = (short*)d_ws;                         // 200000*256 bf16 = 102.4 MB
  short* h1 = rawb + (size_t)N_RAW * 256;             // 100000*256 bf16 = 51.2 MB
  short* W1b = h1 + (size_t)N1 * 256;                 // 131072 bf16
  short* W2b = W1b + 131072;                          // 131072 bf16

  convert_all<<<25128, 256, 0, stream>>>(raw, W1, W2, rawb, W1b, W2b);
  sage_fused<true><<<(N1 + 63) / 64, 512, 0, stream>>>(rawb, nodes1, neigh1, W1b, h1, N1);
  sage_fused<false><<<(N2 + 63) / 64, 512, 0, stream>>>(h1, self2, neigh2, W2b, out, N2);
}